// Round 1
// 584.258 us; speedup vs baseline: 1.0189x; 1.0189x over previous
//
#include <hip/hip_runtime.h>
#include <hip/hip_bf16.h>
#include <stdint.h>

using bf16 = __hip_bfloat16;
typedef short bf16x8 __attribute__((ext_vector_type(8)));
typedef float floatx4 __attribute__((ext_vector_type(4)));

static constexpr int NODES = 2048;
static constexpr int EDGES = 32768;

// pack 8 consecutive f32 -> 8 bf16 (rne) as uint4
__device__ inline uint4 cvt8(const float* __restrict__ p) {
    const float4* f = (const float4*)p;
    float4 a = f[0], b = f[1];
    union { uint4 u; bf16 h[8]; } pk;
    pk.h[0] = __float2bfloat16(a.x); pk.h[1] = __float2bfloat16(a.y);
    pk.h[2] = __float2bfloat16(a.z); pk.h[3] = __float2bfloat16(a.w);
    pk.h[4] = __float2bfloat16(b.x); pk.h[5] = __float2bfloat16(b.y);
    pk.h[6] = __float2bfloat16(b.z); pk.h[7] = __float2bfloat16(b.w);
    return pk.u;
}

// ---------------- generic BMxBN MFMA GEMM body (bf16 MFMA core) ------------
// C[m,n] = epilogue( sum_k A[m,k] * B'[n,k] + bias[n] )
// AMODE 0: A bf16 scratch [M,K]
// AMODE 1: A f32 [M,K] (cvt in staging)
// AMODE 2: A row n = concat(inputsF[n], aggin[n]) f32->bf16 (K=512)
// AMODE 3: A row e = relu(U[sidx[e]][k] + V[ridx[e]][k] + b1[k]), U/V bf16 (K=512)
// BMODE 0: B' = Bt f32 [N,K]
// BMODE 1: B' row n = msg_W1[n&511][ (n>>9)*256 .. +K ]  (split W1 halves)
// BMODE 2: B' = Bt already bf16 [N,K] (pre-converted weights, no cvt)
// EPI 0: +bias, relu, store bf16 Cout[M,N]
// EPI 1: +bias, relu, atomicAdd fp32 into aggout[rIdx[row]*256+n]
// EPI 2: +bias, add f32 residual inputsF[m,n], store f32 OutF (N==256)
// EPI 3: raw f32 store OutF[M,N] (no bias)
// EPI 4: raw bf16 store Cout[M,N] (no bias)
template<int BM, int BN, int AMODE, int BMODE, int EPI>
__device__ __forceinline__ void gemm_body(
    const bf16* __restrict__ A, const float* __restrict__ Af,
    const float* __restrict__ Bt, const float* __restrict__ bias,
    bf16* __restrict__ Cout, float* __restrict__ OutF,
    const float* __restrict__ inputsF, const bf16* __restrict__ UVb,
    const float* __restrict__ b1v, const int* __restrict__ sidx,
    const int* __restrict__ ridx, const float* __restrict__ aggin,
    float* __restrict__ aggout, int M, int N, int K, int bx, int by)
{
    constexpr int BK = 32;
    constexpr int PA = BM / 64;   // A staging passes (16B/thread each)
    constexpr int PB = BN / 64;
    constexpr int MI = BM / 32;   // per-wave 16-tiles in M
    constexpr int NJ = BN / 32;   // per-wave 16-tiles in N
    __shared__ bf16 As[BM * BK];
    __shared__ bf16 Bs[BN * BK];
    __shared__ int sIdx[BM];
    __shared__ int rIdx[BM];

    const int t = threadIdx.x;
    const int m0 = by * BM;
    const int n0 = bx * BN;

    if constexpr (AMODE == 3) {
        if (t < BM) {
            sIdx[t] = sidx[m0 + t] & (NODES - 1);   // OOB structurally impossible
            rIdx[t] = ridx[m0 + t] & (NODES - 1);
        }
        __syncthreads();
    }

    // staging: thread t covers LDS row (p*64 + t/4), 16B bf16 chunk (t%4)
    const int sr = t >> 2;
    const int sc = t & 3;

    uint4 ra[PA], rb[PB];

    auto loadTiles = [&](int kt) {
        const int kk = kt * BK + sc * 8;   // element column within K
#pragma unroll
        for (int p = 0; p < PA; ++p) {
            const int row = p * 64 + sr;
            if constexpr (AMODE == 0) {
                ra[p] = *(const uint4*)(A + (size_t)(m0 + row) * K + kk);
            } else if constexpr (AMODE == 1) {
                ra[p] = cvt8(Af + (size_t)(m0 + row) * K + kk);
            } else if constexpr (AMODE == 2) {
                const float* src = (kk < 256)
                    ? (inputsF + (size_t)(m0 + row) * 256 + kk)
                    : (aggin + (size_t)(m0 + row) * 256 + (kk - 256));
                ra[p] = cvt8(src);
            } else {
                union { uint4 q; unsigned short h[8]; } uu, vv;
                uu.q = *(const uint4*)(UVb + (size_t)sIdx[row] * 1024 + kk);
                vv.q = *(const uint4*)(UVb + (size_t)rIdx[row] * 1024 + 512 + kk);
                const float4* c = (const float4*)(b1v + kk);
                float4 c0 = c[0], c1 = c[1];
                const float cf[8] = {c0.x, c0.y, c0.z, c0.w, c1.x, c1.y, c1.z, c1.w};
                union { uint4 q; bf16 h[8]; } pk;
#pragma unroll
                for (int e = 0; e < 8; ++e) {
                    union { unsigned int u; float f; } a2, b2;
                    a2.u = (unsigned int)uu.h[e] << 16;
                    b2.u = (unsigned int)vv.h[e] << 16;
                    pk.h[e] = __float2bfloat16(fmaxf(a2.f + b2.f + cf[e], 0.f));
                }
                ra[p] = pk.q;
            }
        }
#pragma unroll
        for (int p = 0; p < PB; ++p) {
            const int row = p * 64 + sr;
            if constexpr (BMODE == 0) {
                rb[p] = cvt8(Bt + (size_t)(n0 + row) * K + kk);
            } else if constexpr (BMODE == 2) {
                rb[p] = *(const uint4*)(((const bf16*)Bt) + (size_t)(n0 + row) * K + kk);
            } else {
                const int n = n0 + row;
                rb[p] = cvt8(Bt + (size_t)(n & 511) * 512 + (n >> 9) * 256 + kk);
            }
        }
    };

    const int wv = t >> 6;
    const int lane = t & 63;
    const int wm = wv >> 1, wn = wv & 1;   // wave covers (BM/2)x(BN/2)
    const int r16 = lane & 15, q = lane >> 4;

    floatx4 acc[MI][NJ] = {};

    loadTiles(0);
    const int KT = K / BK;
    for (int kt = 0; kt < KT; ++kt) {
        __syncthreads();
#pragma unroll
        for (int p = 0; p < PA; ++p)
            *(uint4*)(&As[(p * 64 + sr) * BK + sc * 8]) = ra[p];
#pragma unroll
        for (int p = 0; p < PB; ++p)
            *(uint4*)(&Bs[(p * 64 + sr) * BK + sc * 8]) = rb[p];
        __syncthreads();
        if (kt + 1 < KT) loadTiles(kt + 1);   // overlap next-tile loads with MFMA

        bf16x8 af[MI], bfr[NJ];
#pragma unroll
        for (int i = 0; i < MI; ++i)
            af[i] = *(const bf16x8*)(&As[(wm * (BM / 2) + i * 16 + r16) * BK + q * 8]);
#pragma unroll
        for (int j = 0; j < NJ; ++j)
            bfr[j] = *(const bf16x8*)(&Bs[(wn * (BN / 2) + j * 16 + r16) * BK + q * 8]);
#pragma unroll
        for (int i = 0; i < MI; ++i)
#pragma unroll
            for (int j = 0; j < NJ; ++j)
                acc[i][j] = __builtin_amdgcn_mfma_f32_16x16x32_bf16(af[i], bfr[j], acc[i][j], 0, 0, 0);
    }

    float bv[NJ];
#pragma unroll
    for (int j = 0; j < NJ; ++j)
        bv[j] = (EPI == 3 || EPI == 4) ? 0.f : bias[n0 + wn * (BN / 2) + j * 16 + r16];

    // C/D layout: col = lane&15, row = q*4 + r (verified m89/m91)
#pragma unroll
    for (int i = 0; i < MI; ++i) {
        const int lr = wm * (BM / 2) + i * 16 + q * 4;
        const int rbase = m0 + lr;
#pragma unroll
        for (int j = 0; j < NJ; ++j) {
            const int gc = n0 + wn * (BN / 2) + j * 16 + r16;
#pragma unroll
            for (int r = 0; r < 4; ++r) {
                float v = acc[i][j][r] + bv[j];
                const int gr = rbase + r;
                if constexpr (EPI == 0) {
                    v = fmaxf(v, 0.0f);
                    Cout[(size_t)gr * N + gc] = __float2bfloat16(v);
                } else if constexpr (EPI == 1) {
                    v = fmaxf(v, 0.0f);
                    atomicAdd(&aggout[(size_t)rIdx[lr + r] * 256 + gc], v);
                } else if constexpr (EPI == 2) {
                    OutF[(size_t)gr * 256 + gc] = inputsF[(size_t)gr * 256 + gc] + v;
                } else if constexpr (EPI == 3) {
                    OutF[(size_t)gr * N + gc] = v;
                } else {
                    Cout[(size_t)gr * N + gc] = __float2bfloat16(v);
                }
            }
        }
    }
}

template<int BM, int BN, int AMODE, int BMODE, int EPI>
__global__ __launch_bounds__(256, 2) void gemm_k(
    const bf16* __restrict__ A, const float* __restrict__ Af,
    const float* __restrict__ Bt, const float* __restrict__ bias,
    bf16* __restrict__ Cout, float* __restrict__ OutF,
    const float* __restrict__ inputsF, const bf16* __restrict__ UVb,
    const float* __restrict__ b1v, const int* __restrict__ sidx,
    const int* __restrict__ ridx, const float* __restrict__ aggin,
    float* __restrict__ aggout, int M, int N, int K)
{
    gemm_body<BM, BN, AMODE, BMODE, EPI>(A, Af, Bt, bias, Cout, OutF, inputsF,
        UVb, b1v, sidx, ridx, aggin, aggout, M, N, K, blockIdx.x, blockIdx.y);
}

// ---------------- fused node MLP: 3 layers pipelined per 16-row block ------
// Each block owns 16 nodes; layer outputs stay in LDS (bf16, padded stride
// 520 -> bank stride 4 dwords, max 2-way aliasing = free). B fragments are
// double-buffered in registers straight from the L2-resident bf16 weights
// (no LDS staging, no per-tile f32->bf16 repack). Replaces 3 kernel launches
// + 8 MB of g1/g2 HBM round-trip with one ~5 us kernel.
template<int NJ, int EPI>   // EPI 0: relu -> LDS bf16 ; EPI 1: +inputs residual -> f32 global
__device__ __forceinline__ void mlp_layer(
    const bf16* __restrict__ Asrc, const bf16* __restrict__ W,
    const float* __restrict__ bias, bf16* __restrict__ dst,
    const float* __restrict__ inputsF, float* __restrict__ outF,
    int m0, int wv, int r16, int q)
{
    constexpr int LDR = 520;
    const int ncol0 = wv * NJ * 16;
    floatx4 acc[NJ] = {};
    bf16x8 bb0[NJ], bb1[NJ];
    bf16x8 aa0, aa1;

    auto loadB = [&](int kt, bf16x8* d) {
#pragma unroll
        for (int j = 0; j < NJ; ++j)
            d[j] = *(const bf16x8*)(W + (size_t)(ncol0 + j * 16 + r16) * 512 + kt * 32 + q * 8);
    };
    auto loadA = [&](int kt) {
        return *(const bf16x8*)(Asrc + r16 * LDR + kt * 32 + q * 8);
    };

    loadB(0, bb0); aa0 = loadA(0);
#pragma unroll
    for (int kt = 0; kt < 16; kt += 2) {
        loadB(kt + 1, bb1); aa1 = loadA(kt + 1);
#pragma unroll
        for (int j = 0; j < NJ; ++j)
            acc[j] = __builtin_amdgcn_mfma_f32_16x16x32_bf16(aa0, bb0[j], acc[j], 0, 0, 0);
        if (kt + 2 < 16) { loadB(kt + 2, bb0); aa0 = loadA(kt + 2); }
#pragma unroll
        for (int j = 0; j < NJ; ++j)
            acc[j] = __builtin_amdgcn_mfma_f32_16x16x32_bf16(aa1, bb1[j], acc[j], 0, 0, 0);
    }

    // C/D layout: col = lane&15, row = q*4 + r (verified m89/m91)
#pragma unroll
    for (int j = 0; j < NJ; ++j) {
        const int gc = ncol0 + j * 16 + r16;
        const float bvv = bias[gc];
#pragma unroll
        for (int r = 0; r < 4; ++r) {
            float v = acc[j][r] + bvv;
            const int lr = q * 4 + r;
            if constexpr (EPI == 0) {
                dst[lr * LDR + gc] = __float2bfloat16(fmaxf(v, 0.f));
            } else {
                const size_t o = (size_t)(m0 + lr) * 256 + gc;
                outF[o] = inputsF[o] + v;
            }
        }
    }
}

__global__ __launch_bounds__(256, 2) void node_mlp(
    const float* __restrict__ inputs, const float* __restrict__ agg,
    const bf16* __restrict__ W1b, const float* __restrict__ b1,
    const bf16* __restrict__ W2b, const float* __restrict__ b2,
    const bf16* __restrict__ W3b, const float* __restrict__ b3,
    float* __restrict__ out)
{
    constexpr int LDR = 520;
    __shared__ bf16 As[16 * LDR];
    __shared__ bf16 Hs[16 * LDR];
    __shared__ bf16 Gs[16 * LDR];
    const int t = threadIdx.x;
    const int m0 = blockIdx.x * 16;

    // stage A = concat(inputs, agg) rows m0..m0+15 as bf16 (coalesced 32B/lane)
#pragma unroll
    for (int p = 0; p < 4; ++p) {
        const int c = t + 256 * p;          // 1024 chunks of 8 elems
        const int row = c >> 6;
        const int col = (c & 63) * 8;
        const float* src = (col < 256)
            ? (inputs + (size_t)(m0 + row) * 256 + col)
            : (agg + (size_t)(m0 + row) * 256 + (col - 256));
        *(uint4*)(&As[row * LDR + col]) = cvt8(src);
    }
    const int wv = t >> 6, lane = t & 63;
    const int r16 = lane & 15, q = lane >> 4;
    __syncthreads();
    mlp_layer<8, 0>(As, W1b, b1, Hs, nullptr, nullptr, m0, wv, r16, q);
    __syncthreads();
    mlp_layer<8, 0>(Hs, W2b, b2, Gs, nullptr, nullptr, m0, wv, r16, q);
    __syncthreads();
    mlp_layer<4, 1>(Gs, W3b, b3, nullptr, inputs, out, m0, wv, r16, q);
}

// ---------------- fat front kernel: UV GEMM + zero + weight cvt + extract --
// blocks [0,512):      UV(bf16) = inputs @ [W1_left|W1_right]^T (64x64 tiles)
//                      -- FIRST so they start before the extract flood
// blocks [512,1024):   zero agg (2 MB)
// blocks [1024,1408):  f32->bf16 weight conversion (msg_W2|out_W1|out_W2|out_W3)
// blocks [1408,17792): one-hot index extraction (one wave per row, early exit)
// __launch_bounds__(256,8): cap 64 VGPR so the extract waves keep 8 waves/SIMD
// (extract is HBM-latency-bound, 1 load in flight/wave: occupancy IS bandwidth)
__global__ __launch_bounds__(256, 8) void fat_pre(
    const float* __restrict__ rel_rec, const float* __restrict__ rel_send,
    int* __restrict__ recv_idx, int* __restrict__ send_idx,
    float4* __restrict__ agg, const float* __restrict__ inputs,
    const float* __restrict__ msg_W1, bf16* __restrict__ UVb,
    const float* __restrict__ msg_W2, const float* __restrict__ out_W1,
    const float* __restrict__ out_W2, const float* __restrict__ out_W3,
    bf16* __restrict__ Wc)
{
    const int b = blockIdx.x;
    if (b < 512) {
        gemm_body<64, 64, 1, 1, 4>(nullptr, inputs, msg_W1, nullptr, UVb, nullptr,
            nullptr, nullptr, nullptr, nullptr, nullptr, nullptr, nullptr,
            NODES, 1024, 256, b & 15, b >> 4);
    } else if (b < 1024) {
        agg[(size_t)(b - 512) * 256 + threadIdx.x] = float4{0.f, 0.f, 0.f, 0.f};
    } else if (b < 1408) {
        // one-shot weight cvt: gid ranges are block-uniform (boundaries are
        // multiples of 2048), dst is contiguous [msgW2|outW1|outW2|outW3]
        const int gid = (b - 1024) * 2048 + threadIdx.x * 8;
        const float* src;
        if (gid < 131072)      src = msg_W2 + gid;
        else if (gid < 393216) src = out_W1 + (gid - 131072);
        else if (gid < 655360) src = out_W2 + (gid - 393216);
        else                   src = out_W3 + (gid - 655360);
        *(uint4*)(Wc + gid) = cvt8(src);
    } else {
        const int eb = b - 1408;
        const int half = eb >> 13;         // 0: rel_rec, 1: rel_send
        const int rb = eb & 8191;
        const float* mat = half ? rel_send : rel_rec;
        int* out = half ? send_idx : recv_idx;
        const int w = threadIdx.x >> 6;
        const int lane = threadIdx.x & 63;
        const int row = rb * 4 + w;        // 0..32767
        if (lane == 0) out[row] = 0;       // defensive init
        const uint4* base = (const uint4*)(mat + (size_t)row * NODES);
        for (int p = 0; p < 8; ++p) {
            uint4 v = base[p * 64 + lane];
            const bool hit = (v.x | v.y | v.z | v.w) != 0u;
            if (hit) {
                int e = v.x ? 0 : (v.y ? 1 : (v.z ? 2 : 3));
                out[row] = p * 256 + lane * 4 + e;
            }
            if (__any(hit)) break;         // wave early exit (avg ~4.5/8 passes)
        }
    }
}

extern "C" void kernel_launch(void* const* d_in, const int* in_sizes, int n_in,
                              void* d_out, int out_size, void* d_ws, size_t ws_size,
                              hipStream_t stream) {
    const float* inputs   = (const float*)d_in[0];
    const float* rel_rec  = (const float*)d_in[1];
    const float* rel_send = (const float*)d_in[2];
    const float* msg_W1   = (const float*)d_in[3];
    const float* msg_b1   = (const float*)d_in[4];
    const float* msg_W2   = (const float*)d_in[5];
    const float* msg_b2   = (const float*)d_in[6];
    const float* out_W1   = (const float*)d_in[7];
    const float* out_b1   = (const float*)d_in[8];
    const float* out_W2   = (const float*)d_in[9];
    const float* out_b2   = (const float*)d_in[10];
    const float* out_W3   = (const float*)d_in[11];
    const float* out_b3   = (const float*)d_in[12];

    // workspace layout (~7.8 MB used)
    char* ws = (char*)d_ws;
    int*   recv_idx = (int*)(ws + 0);            // 128 KB
    int*   send_idx = (int*)(ws + 131072);       // 128 KB
    float* agg      = (float*)(ws + 262144);     // 2 MB fp32 [2048,256]
    bf16*  UVb      = (bf16*)(ws + 2359296);     // 4 MB bf16 [2048,1024] (U|V)
    bf16*  Wc       = (bf16*)(ws + 6553600);     // 1.5 MB bf16 [msgW2|oW1|oW2|oW3]
    bf16*  W2b  = Wc;                            // 256x512
    bf16*  oW1b = Wc + 131072;                   // 512x512
    bf16*  oW2b = Wc + 393216;                   // 512x512
    bf16*  oW3b = Wc + 655360;                   // 256x512
    if (ws_size < (size_t)11 * 1024 * 1024) return;  // fail loudly, not fault

    // 1) fused: UV GEMM (first!) + agg zeroing + weight cvt + index extraction
    fat_pre<<<17792, 256, 0, stream>>>(rel_rec, rel_send, recv_idx, send_idx,
                                       (float4*)agg, inputs, msg_W1, UVb,
                                       msg_W2, out_W1, out_W2, out_W3, Wc);

    // 2) fused edge layer-2 + scatter (R6-measured-best 128x128 tile),
    //    B now pre-converted bf16 (BMODE 2 -> no per-tile repack):
    //    agg[recv[e]] += relu( relu(U[send[e]]+V[recv[e]]+b1) @ W2^T + b2 )
    gemm_k<128, 128, 3, 2, 1><<<dim3(2, 256), 256, 0, stream>>>(
        nullptr, nullptr, (const float*)W2b, msg_b2, nullptr, nullptr,
        nullptr, UVb, msg_b1, send_idx, recv_idx, nullptr, agg,
        EDGES, 256, 512);

    // 3) fused node MLP (replaces 3 GEMM launches + g1/g2 HBM round-trip):
    //    out = inputs + mlp3(concat(inputs, agg))
    node_mlp<<<128, 256, 0, stream>>>(
        inputs, agg, oW1b, out_b1, oW2b, out_b2, oW3b, out_b3, (float*)d_out);
}